// Round 1
// baseline (1625.960 us; speedup 1.0000x reference)
//
#include <hip/hip_runtime.h>
#include <hip/hip_bf16.h>

// Problem: B=128, T=512, I=128, H=256, O=1 (all fp32)
// out[b] = sigmoid( b_fc + sum_j h_T[b][j] * W_fc[j] )
// h_t = tanh( xp_t + h_{t-1} @ W_hh^T ),  xp = x @ W_ih^T + b_ih + b_hh

#define B_ 128
#define T_ 512
#define I_ 128
#define H_ 256
#define MT 64   // rows (b*t) per block in the xp GEMM

__device__ __forceinline__ float tanh_fast(float x) {
    // tanh(x) = 1 - 2/(exp(2x)+1); saturates correctly for |x| large
    float e = __expf(2.0f * x);
    return 1.0f - 2.0f / (e + 1.0f);
}

// ---------------- Kernel A: xp[m][j] = b_ih[j]+b_hh[j] + sum_i x[m][i]*W_ih[j][i]
__global__ __launch_bounds__(256, 1)
void xp_gemm_kernel(const float* __restrict__ x, const float* __restrict__ W_ih,
                    const float* __restrict__ b_ih, const float* __restrict__ b_hh,
                    float* __restrict__ xp) {
    __shared__ float xs[MT][I_];   // 32 KB
    const int j = threadIdx.x;          // output column 0..255
    const long m0 = (long)blockIdx.x * MT;

    // W_ih row j -> 128 VGPRs
    float w[I_];
    const float4* wr = (const float4*)(W_ih + (long)j * I_);
#pragma unroll
    for (int i = 0; i < I_ / 4; ++i) {
        float4 v = wr[i];
        w[4*i+0] = v.x; w[4*i+1] = v.y; w[4*i+2] = v.z; w[4*i+3] = v.w;
    }
    const float bias = b_ih[j] + b_hh[j];

    // stage x tile (MT*I_ floats, contiguous since x is [B*T][I] row-major)
    const float4* xsrc = (const float4*)(x + m0 * I_);
    float4* xdst = (float4*)(&xs[0][0]);
#pragma unroll
    for (int r = 0; r < (MT * I_ / 4) / 256; ++r)
        xdst[r * 256 + j] = xsrc[r * 256 + j];
    __syncthreads();

#pragma unroll 1
    for (int m = 0; m < MT; ++m) {
        float acc = bias;
#pragma unroll
        for (int i = 0; i < I_; ++i) acc += xs[m][i] * w[i];
        xp[(m0 + m) * H_ + j] = acc;
    }
}

// ---------------- Kernel B: per-batch recurrence + fused head
__global__ __launch_bounds__(256, 1)
void rnn_kernel(const float* __restrict__ xp, const float* __restrict__ W_hh,
                const float* __restrict__ W_fc, const float* __restrict__ b_fc,
                float* __restrict__ out) {
    __shared__ float hsh[H_];
    __shared__ float red[4];
    const int j = threadIdx.x;     // hidden unit 0..255
    const int b = blockIdx.x;      // batch element

    // W_hh row j -> 256 VGPRs (stays resident across all 512 steps)
    float w[H_];
    const float4* wr = (const float4*)(W_hh + (long)j * H_);
#pragma unroll
    for (int k = 0; k < H_ / 4; ++k) {
        float4 v = wr[k];
        w[4*k+0] = v.x; w[4*k+1] = v.y; w[4*k+2] = v.z; w[4*k+3] = v.w;
    }

    hsh[j] = 0.0f;
    const float* xpb = xp + (long)b * T_ * H_ + j;
    __syncthreads();

    float h = 0.0f;
#pragma unroll 1
    for (int t = 0; t < T_; ++t) {
        const float xv = xpb[(long)t * H_];   // prefetch; consumed after FMA loop
        float acc = 0.0f;
#pragma unroll
        for (int k = 0; k < H_; ++k) acc += hsh[k] * w[k];
        acc += xv;
        const float hn = tanh_fast(acc);
        __syncthreads();              // all lanes done reading hsh
        hsh[j] = hn;
        h = hn;
        __syncthreads();              // new h visible
    }

    // head: out[b] = sigmoid(b_fc + sum_j h_j * W_fc[j])
    float p = h * W_fc[j];
#pragma unroll
    for (int off = 32; off > 0; off >>= 1) p += __shfl_down(p, off);
    if ((j & 63) == 0) red[j >> 6] = p;
    __syncthreads();
    if (j == 0) {
        float tot = red[0] + red[1] + red[2] + red[3] + b_fc[0];
        out[b] = 1.0f / (1.0f + __expf(-tot));
    }
}

extern "C" void kernel_launch(void* const* d_in, const int* in_sizes, int n_in,
                              void* d_out, int out_size, void* d_ws, size_t ws_size,
                              hipStream_t stream) {
    const float* x    = (const float*)d_in[0];
    const float* W_ih = (const float*)d_in[1];
    const float* W_hh = (const float*)d_in[2];
    const float* b_ih = (const float*)d_in[3];
    const float* b_hh = (const float*)d_in[4];
    const float* W_fc = (const float*)d_in[5];
    const float* b_fc = (const float*)d_in[6];
    float* out = (float*)d_out;

    float* xp = (float*)d_ws;   // B*T*H fp32 = 67.1 MB

    xp_gemm_kernel<<<(B_ * T_) / MT, 256, 0, stream>>>(x, W_ih, b_ih, b_hh, xp);
    rnn_kernel<<<B_, 256, 0, stream>>>(xp, W_hh, W_fc, b_fc, out);
}

// Round 2
// 691.287 us; speedup vs baseline: 2.3521x; 2.3521x over previous
//
#include <hip/hip_runtime.h>
#include <hip/hip_bf16.h>

// B=128, T=512, I=128, H=256, O=1 (fp32)
// xp = x @ W_ih^T + b_ih + b_hh ;  h_t = tanh(xp_t + h @ W_hh^T) ; out = sigmoid(h_T @ W_fc^T + b_fc)

#define B_ 128
#define T_ 512
#define I_ 128
#define H_ 256

__device__ __forceinline__ float tanh_fast(float x) {
    float e = __expf(2.0f * x);
    return 1.0f - 2.0f / (e + 1.0f);
}

// ---------------- Kernel A: xp[m][n] = bias[n] + sum_k x[m][k]*W_ih[n][k]
// 128x128 output tile, 8x8 microtile/thread, K=128 in 2 stages of 64.
// LDS rows padded to 17 float4 (68 floats); quad index XOR-swizzled by (row>>3)&15
// so inner-loop reads are 2-way-or-less bank aliased (free).
__global__ __launch_bounds__(256, 2)
void xp_gemm_kernel(const float* __restrict__ x, const float* __restrict__ W_ih,
                    const float* __restrict__ b_ih, const float* __restrict__ b_hh,
                    float* __restrict__ xp) {
    __shared__ float4 As4[128 * 17];   // As[m][k] swizzled, 34.8 KB
    __shared__ float4 Bs4[128 * 17];   // Bs[n][k] swizzled
    const int tid = threadIdx.x;
    const int tx = tid & 15;           // m-microtile index
    const int ty = tid >> 4;           // n-microtile index
    const long m0 = (long)(blockIdx.x >> 1) * 128;
    const int  n0 = (blockIdx.x & 1) * 128;

    float bias[8];
#pragma unroll
    for (int j = 0; j < 8; ++j) {
        int n = n0 + ty * 8 + j;
        bias[j] = b_ih[n] + b_hh[n];
    }

    float acc[8][8];
#pragma unroll
    for (int i = 0; i < 8; ++i)
#pragma unroll
        for (int j = 0; j < 8; ++j) acc[i][j] = 0.0f;

#pragma unroll 1
    for (int s = 0; s < 2; ++s) {
        const int ks = s * 64;
        // stage: each thread loads 8 float4 of x-tile and 8 of W-tile (coalesced rows)
#pragma unroll
        for (int r = 0; r < 8; ++r) {
            int f = r * 256 + tid;
            int m = f >> 4, kc = f & 15;
            int sw = kc ^ ((m >> 3) & 15);
            As4[m * 17 + sw] = *(const float4*)(x    + (m0 + m) * I_ + ks + kc * 4);
            Bs4[m * 17 + sw] = *(const float4*)(W_ih + (long)(n0 + m) * I_ + ks + kc * 4);
        }
        __syncthreads();

#pragma unroll 2
        for (int kq = 0; kq < 16; ++kq) {
            float4 a[8], b[8];
#pragma unroll
            for (int i = 0; i < 8; ++i) a[i] = As4[(tx * 8 + i) * 17 + (kq ^ tx)];
#pragma unroll
            for (int j = 0; j < 8; ++j) b[j] = Bs4[(ty * 8 + j) * 17 + (kq ^ ty)];
#pragma unroll
            for (int i = 0; i < 8; ++i)
#pragma unroll
                for (int j = 0; j < 8; ++j)
                    acc[i][j] += a[i].x * b[j].x + a[i].y * b[j].y
                               + a[i].z * b[j].z + a[i].w * b[j].w;
        }
        __syncthreads();
    }

    // epilogue: add bias, store two float4 per row
#pragma unroll
    for (int i = 0; i < 8; ++i) {
        long row = m0 + tx * 8 + i;
        float4 o0, o1;
        o0.x = acc[i][0] + bias[0]; o0.y = acc[i][1] + bias[1];
        o0.z = acc[i][2] + bias[2]; o0.w = acc[i][3] + bias[3];
        o1.x = acc[i][4] + bias[4]; o1.y = acc[i][5] + bias[5];
        o1.z = acc[i][6] + bias[6]; o1.w = acc[i][7] + bias[7];
        float* p = xp + row * H_ + n0 + ty * 8;
        *(float4*)(p)     = o0;
        *(float4*)(p + 4) = o1;
    }
}

// ---------------- Kernel B: per-batch recurrence + fused head
// 512 threads = 128 j-slots (2 hidden units each) x 4 k-groups (64 k each).
// Thread holds 2x64 = 128 W_hh floats in VGPRs (no reload!). k-groups take
// INTERLEAVED k-quads (quad q = 4i+kg) so the 4 broadcast address groups per
// ds_read hit distinct banks. Partials reduced with 2 shfl_xor (kg is lane&3).
__global__ __launch_bounds__(512, 2)
void rnn_kernel(const float* __restrict__ xp, const float* __restrict__ W_hh,
                const float* __restrict__ W_fc, const float* __restrict__ b_fc,
                float* __restrict__ out) {
    __shared__ float hsh[H_];
    __shared__ float red[8];
    const int tid   = threadIdx.x;
    const int kg    = tid & 3;        // k-group (lane bits 0-1)
    const int jslot = tid >> 2;       // 0..127
    const int j0    = jslot * 2;
    const int b     = blockIdx.x;

    // resident W_hh fragments: rows j0, j0+1, k-quads {kg, kg+4, ..., kg+60}
    float4 w0[16], w1[16];
    const float* wr = W_hh + (long)j0 * H_;
#pragma unroll
    for (int i = 0; i < 16; ++i) {
        int q = 4 * i + kg;
        w0[i] = *(const float4*)(wr + q * 4);
        w1[i] = *(const float4*)(wr + H_ + q * 4);
    }

    if (tid < H_) hsh[tid] = 0.0f;
    const float2* xp2 = (const float2*)(xp + (long)b * T_ * H_);
    __syncthreads();

#pragma unroll 1
    for (int t = 0; t < T_; ++t) {
        const float2 xv = xp2[t * (H_ / 2) + jslot];  // prefetch; used after FMA loop
        const float4* hq = (const float4*)hsh;
        float acc0 = 0.0f, acc1 = 0.0f;
#pragma unroll
        for (int i = 0; i < 16; ++i) {
            float4 h4 = hq[4 * i + kg];
            acc0 += h4.x * w0[i].x + h4.y * w0[i].y + h4.z * w0[i].z + h4.w * w0[i].w;
            acc1 += h4.x * w1[i].x + h4.y * w1[i].y + h4.z * w1[i].z + h4.w * w1[i].w;
        }
        // reduce over 4 k-groups (lanes j*4+0..3)
        acc0 += __shfl_xor(acc0, 1); acc0 += __shfl_xor(acc0, 2);
        acc1 += __shfl_xor(acc1, 1); acc1 += __shfl_xor(acc1, 2);
        __syncthreads();              // all reads of hsh complete
        if (kg == 0) {
            float hn0 = tanh_fast(acc0 + xv.x);
            float hn1 = tanh_fast(acc1 + xv.y);
            ((float2*)hsh)[jslot] = make_float2(hn0, hn1);
        }
        __syncthreads();              // new h visible
    }

    // head: out[b] = sigmoid(b_fc + sum_j h[j]*W_fc[j])
    float p = (tid < H_) ? hsh[tid] * W_fc[tid] : 0.0f;
#pragma unroll
    for (int off = 32; off > 0; off >>= 1) p += __shfl_down(p, off);
    if ((tid & 63) == 0) red[tid >> 6] = p;
    __syncthreads();
    if (tid == 0) {
        float tot = b_fc[0];
#pragma unroll
        for (int i = 0; i < 8; ++i) tot += red[i];
        out[b] = 1.0f / (1.0f + __expf(-tot));
    }
}

extern "C" void kernel_launch(void* const* d_in, const int* in_sizes, int n_in,
                              void* d_out, int out_size, void* d_ws, size_t ws_size,
                              hipStream_t stream) {
    const float* x    = (const float*)d_in[0];
    const float* W_ih = (const float*)d_in[1];
    const float* W_hh = (const float*)d_in[2];
    const float* b_ih = (const float*)d_in[3];
    const float* b_hh = (const float*)d_in[4];
    const float* W_fc = (const float*)d_in[5];
    const float* b_fc = (const float*)d_in[6];
    float* out = (float*)d_out;

    float* xp = (float*)d_ws;   // B*T*H fp32 = 67.1 MB scratch

    xp_gemm_kernel<<<(B_ * T_ / 128) * (H_ / 128), 256, 0, stream>>>(x, W_ih, b_ih, b_hh, xp);
    rnn_kernel<<<B_, 512, 0, stream>>>(xp, W_hh, W_fc, b_fc, out);
}